// Round 1
// baseline (425.617 us; speedup 1.0000x reference)
//
#include <hip/hip_runtime.h>

// ---------------------------------------------------------------------------
// DoubleLayeredEncoder: 2-layer GCN + PReLU + half-sum. N=100k, E=1.6M.
// R6: attack k_ell_gemm1 (latency-bound: 12% HBM / 22% VALU / 0 MFMA).
//  - ELL build: 8 edges/thread (was 2). int4 edge loads, 8 atomics issued
//    back-to-back, then 8 predicated scatter stores -> 4x in-flight chains.
//  - gemm1 staging: row-major padded x-tile xs[32][132] (was transposed
//    stride-32 = 32-way bank conflict, SQ_LDS_BANK_CONFLICT=1.24e7).
//    Stores: contiguous float4 (conflict-free). Reads: b128 along k,
//    2 distinct addrs/wave (broadcast, conflict-free).
// Pipeline: memset(cnt) -> k_ell_gemm1 -> k_dinv -> k_g1g2 -> k_g2h
// ---------------------------------------------------------------------------

#define ELL_CAP 64

__device__ __forceinline__ unsigned bf16rne(float x) {
    unsigned u = __float_as_uint(x);
    return (u + 0x7FFFu + ((u >> 16) & 1u)) >> 16;
}
__device__ __forceinline__ unsigned pack2bf(float a, float b) {
    return bf16rne(a) | (bf16rne(b) << 16);
}

// ---- heterogeneous: blocks [0,G_ell) build ELL, rest do gemm1 --------------
__global__ __launch_bounds__(256) void k_ell_gemm1(
    const int* __restrict__ src, const int* __restrict__ dst,
    const int* __restrict__ et, const float* __restrict__ ew,
    int* __restrict__ cnt, int2* __restrict__ ell, int E,
    const float* __restrict__ x, const float* __restrict__ W,
    unsigned* __restrict__ xb1, int n, int G_ell) {
    __shared__ float xs[32 * 132];   // row-major x-tile, pad 128->132, 16.9 KB
    int t = threadIdx.x;

    if ((int)blockIdx.x < G_ell) {
        // ---- ELL build: 8 edges/thread for MLP ----
        int e0 = (blockIdx.x * 256 + t) * 8;
        if (e0 + 8 <= E) {
            int4 sa = *(const int4*)(src + e0), sb = *(const int4*)(src + e0 + 4);
            int4 da = *(const int4*)(dst + e0), db = *(const int4*)(dst + e0 + 4);
            int4 ta = *(const int4*)(et + e0),  tb = *(const int4*)(et + e0 + 4);
            float4 wa = *(const float4*)(ew + e0), wb = *(const float4*)(ew + e0 + 4);
            int   s[8]  = {sa.x, sa.y, sa.z, sa.w, sb.x, sb.y, sb.z, sb.w};
            int   d[8]  = {da.x, da.y, da.z, da.w, db.x, db.y, db.z, db.w};
            int   tt[8] = {ta.x, ta.y, ta.z, ta.w, tb.x, tb.y, tb.z, tb.w};
            float w[8]  = {wa.x, wa.y, wa.z, wa.w, wb.x, wb.y, wb.z, wb.w};
            int p[8];
#pragma unroll
            for (int i = 0; i < 8; i++) p[i] = atomicAdd(&cnt[d[i]], 1);
#pragma unroll
            for (int i = 0; i < 8; i++)
                if (p[i] < ELL_CAP)
                    ell[d[i] * ELL_CAP + p[i]] =
                        make_int2(s[i] | (tt[i] << 24), __float_as_int(w[i]));
        } else if (e0 < E) {
            // tail (last block only)
            for (int i = 0; i < E - e0; i++) {
                int di = dst[e0 + i];
                int p = atomicAdd(&cnt[di], 1);
                if (p < ELL_CAP)
                    ell[di * ELL_CAP + p] =
                        make_int2(src[e0 + i] | (et[e0 + i] << 24),
                                  __float_as_int(ew[e0 + i]));
            }
        }
        return;
    }

    // ---- gemm1: 32 rows/block, W from global (L2-resident), bf16 out ----
    int row0 = ((int)blockIdx.x - G_ell) * 32;
    const float4* x4 = (const float4*)x;
#pragma unroll
    for (int i = 0; i < 4; i++) {
        int q = t + 256 * i;             // 0..1023
        int r = q >> 5;                  // row 0..31
        int cq = q & 31;                 // float4 col group
        int row = row0 + r;
        float4 v = make_float4(0.f, 0.f, 0.f, 0.f);
        if (row < n) v = x4[row * 32 + cq];
        *(float4*)&xs[r * 132 + (cq << 2)] = v;   // contiguous, conflict-free
    }
    __syncthreads();

    int c = t & 31;                      // W column group (4 cols)
    int r4 = (t >> 5) << 2;              // row group base
    const float4* W4 = (const float4*)W;
    float acc[4][4] = {};
#pragma unroll 4
    for (int k4 = 0; k4 < 128; k4 += 4) {
        float4 xr[4];
#pragma unroll
        for (int i = 0; i < 4; i++)
            xr[i] = *(const float4*)&xs[(r4 + i) * 132 + k4];  // broadcast read
        float4 wv[4];
#pragma unroll
        for (int j = 0; j < 4; j++)
            wv[j] = W4[(k4 + j) * 32 + c];
#pragma unroll
        for (int i = 0; i < 4; i++) {
            acc[i][0] += xr[i].x * wv[0].x + xr[i].y * wv[1].x + xr[i].z * wv[2].x + xr[i].w * wv[3].x;
            acc[i][1] += xr[i].x * wv[0].y + xr[i].y * wv[1].y + xr[i].z * wv[2].y + xr[i].w * wv[3].y;
            acc[i][2] += xr[i].x * wv[0].z + xr[i].y * wv[1].z + xr[i].z * wv[2].z + xr[i].w * wv[3].z;
            acc[i][3] += xr[i].x * wv[0].w + xr[i].y * wv[1].w + xr[i].z * wv[2].w + xr[i].w * wv[3].w;
        }
    }
#pragma unroll
    for (int i = 0; i < 4; i++) {
        int row = row0 + r4 + i;
        if (row < n) {
            uint2 o = make_uint2(pack2bf(acc[i][0], acc[i][1]),
                                 pack2bf(acc[i][2], acc[i][3]));
            ((uint2*)xb1)[row * 32 + c] = o;
        }
    }
}

// ---- weighted degrees + rsqrt, wave-cooperative (coalesced row reads) ------
__global__ __launch_bounds__(256) void k_dinv(const int* __restrict__ cnt,
                                              const int2* __restrict__ ell,
                                              float* __restrict__ dinv1,
                                              float* __restrict__ dinv2, int n) {
    int t = threadIdx.x;
    int d = blockIdx.x * 16 + (t >> 4);
    int g = t & 15;
    float s1 = 0.f, s2 = 0.f;
    if (d < n) {
        int len = min(cnt[d], ELL_CAP);
        const int2* row = ell + (size_t)d * ELL_CAP;
        for (int kk = g; kk < len; kk += 16) {
            int2 e = row[kk];
            s1 += __int_as_float(e.y);
            s2 += (float)(((unsigned)e.x) >> 24);
        }
    }
#pragma unroll
    for (int o = 8; o >= 1; o >>= 1) {
        s1 += __shfl_xor(s1, o, 16);
        s2 += __shfl_xor(s2, o, 16);
    }
    if (d < n && g == 0) {
        dinv1[d] = rsqrtf(1.0f + s1);
        dinv2[d] = rsqrtf(1.0f + s2);
    }
}

// ---- gather layer 1 (+dinv, bias, PReLU) fused with gemm2 -> xb2 -----------
// 8 nodes/block, 32 lanes/node. h1 tile through LDS; W2 as bf16 in LDS.
__global__ __launch_bounds__(256) void k_g1g2(const int* __restrict__ cnt,
                                              const int2* __restrict__ ell,
                                              const unsigned* __restrict__ xb1,
                                              const float* __restrict__ dinv1,
                                              const float* __restrict__ b,
                                              const float* __restrict__ alpha,
                                              const float* __restrict__ W2,
                                              unsigned* __restrict__ xb2, int n) {
    __shared__ unsigned W2s[128 * 32];   // bf16-packed pairs of cols, 16 KB
    __shared__ float hs[8 * 128];        // h1 tile, 4 KB
    int t = threadIdx.x;

    // pack W2 (128x64 fp32) -> bf16 pairs: W2s[k*32+l] = cols (2l, 2l+1)
    const float2* W22 = (const float2*)W2;
#pragma unroll
    for (int i = 0; i < 16; i++) {
        int idx = t + 256 * i;           // 0..4095
        float2 v = W22[idx];
        W2s[idx] = pack2bf(v.x, v.y);
    }

    int nl = t >> 5;                     // node slot 0..7
    int g = t & 31;
    int d = blockIdx.x * 8 + nl;
    bool active = d < n;
    int len = active ? min(cnt[d], ELL_CAP) : 0;
    const int2* row = ell + (size_t)d * ELL_CAP;
    const uint2* x2 = (const uint2*)xb1;

    float a0 = 0.f, a1v_ = 0.f, a2v_ = 0.f, a3 = 0.f;
    for (int k0 = 0; k0 < len; k0 += 32) {
        int kk = k0 + g;
        int2 ent = (kk < len) ? row[kk] : make_int2(0, 0);
        float cf = 0.f;
        if (kk < len) cf = __int_as_float(ent.y) * dinv1[ent.x & 0xFFFFFF];  // w*dinv1[src]
        int m = min(32, len - k0);
        for (int j = 0; j < m; j++) {
            int pej = __shfl(ent.x, j, 32);
            float cj = __shfl(cf, j, 32);
            int s = pej & 0xFFFFFF;
            uint2 q = x2[s * 32 + g];
            a0 += __uint_as_float(q.x << 16) * cj;
            a1v_ += __uint_as_float(q.x & 0xFFFF0000u) * cj;
            a2v_ += __uint_as_float(q.y << 16) * cj;
            a3 += __uint_as_float(q.y & 0xFFFF0000u) * cj;
        }
    }

    if (active) {
        float di = dinv1[d];
        uint2 sq = x2[d * 32 + g];
        float s0 = __uint_as_float(sq.x << 16);
        float s1 = __uint_as_float(sq.x & 0xFFFF0000u);
        float s2 = __uint_as_float(sq.y << 16);
        float s3 = __uint_as_float(sq.y & 0xFFFF0000u);
        int c4 = g << 2;
        float4 bv = *(const float4*)&b[c4];
        float4 av = *(const float4*)&alpha[c4];
        float v0 = di * (a0 + s0 * di) + bv.x; v0 = v0 >= 0.f ? v0 : av.x * v0;
        float v1 = di * (a1v_ + s1 * di) + bv.y; v1 = v1 >= 0.f ? v1 : av.y * v1;
        float v2 = di * (a2v_ + s2 * di) + bv.z; v2 = v2 >= 0.f ? v2 : av.z * v2;
        float v3 = di * (a3 + s3 * di) + bv.w; v3 = v3 >= 0.f ? v3 : av.w * v3;
        *(float4*)&hs[nl * 128 + c4] = make_float4(v0, v1, v2, v3);
    }
    __syncthreads();

    // gemm2: out[nl][2g], out[nl][2g+1] = hs[nl][:] . W2[:, 2g(+1)]
    float o0 = 0.f, o1 = 0.f;
#pragma unroll 4
    for (int k = 0; k < 128; k++) {
        float hv = hs[nl * 128 + k];
        unsigned pw = W2s[k * 32 + g];
        o0 += hv * __uint_as_float(pw << 16);
        o1 += hv * __uint_as_float(pw & 0xFFFF0000u);
    }
    if (active) xb2[d * 32 + g] = pack2bf(o0, o1);
}

// ---- gather layer 2 (+dinv, bias, PReLU) fused with half-sum readout -------
// 8 node-pairs (j, j+half)/block, 16 lanes/node. Skip etype==0 edges.
__global__ __launch_bounds__(256) void k_g2h(const int* __restrict__ cnt,
                                             const int2* __restrict__ ell,
                                             const unsigned* __restrict__ xb2,
                                             const float* __restrict__ dinv2,
                                             const float* __restrict__ b,
                                             const float* __restrict__ alpha,
                                             float* __restrict__ out, int half) {
    __shared__ float fs[8 * 64];         // second-half results, 2 KB
    int t = threadIdx.x;
    int slot = t >> 4;                   // 0..15
    int g = t & 15;
    int base = blockIdx.x * 8;
    int j = base + ((slot < 8) ? slot : (slot - 8));
    int d = (slot < 8) ? j : (j + half);
    bool active = j < half;
    int len = active ? min(cnt[d], ELL_CAP) : 0;
    const int2* row = ell + (size_t)d * ELL_CAP;
    const uint2* x2 = (const uint2*)xb2;

    float a0 = 0.f, a1v_ = 0.f, a2v_ = 0.f, a3 = 0.f;
    for (int k0 = 0; k0 < len; k0 += 16) {
        int kk = k0 + g;
        int2 ent = (kk < len) ? row[kk] : make_int2(0, 0);
        float cf = 0.f;
        if (kk < len) {
            int tt = ((unsigned)ent.x) >> 24;
            if (tt) cf = (float)tt * dinv2[ent.x & 0xFFFFFF];   // et*dinv2[src]
        }
        int m = min(16, len - k0);
        for (int jj = 0; jj < m; jj++) {
            int pej = __shfl(ent.x, jj, 16);
            float cj = __shfl(cf, jj, 16);
            if (cj != 0.f) {
                int s = pej & 0xFFFFFF;
                uint2 q = x2[s * 16 + g];
                a0 += __uint_as_float(q.x << 16) * cj;
                a1v_ += __uint_as_float(q.x & 0xFFFF0000u) * cj;
                a2v_ += __uint_as_float(q.y << 16) * cj;
                a3 += __uint_as_float(q.y & 0xFFFF0000u) * cj;
            }
        }
    }

    float f0 = 0.f, f1 = 0.f, f2 = 0.f, f3 = 0.f;
    if (active) {
        float di = dinv2[d];
        uint2 sq = x2[d * 16 + g];
        float s0 = __uint_as_float(sq.x << 16);
        float s1 = __uint_as_float(sq.x & 0xFFFF0000u);
        float s2 = __uint_as_float(sq.y << 16);
        float s3 = __uint_as_float(sq.y & 0xFFFF0000u);
        int c4 = g << 2;
        float4 bv = *(const float4*)&b[c4];
        float4 av = *(const float4*)&alpha[c4];
        f0 = di * (a0 + s0 * di) + bv.x; f0 = f0 >= 0.f ? f0 : av.x * f0;
        f1 = di * (a1v_ + s1 * di) + bv.y; f1 = f1 >= 0.f ? f1 : av.y * f1;
        f2 = di * (a2v_ + s2 * di) + bv.z; f2 = f2 >= 0.f ? f2 : av.z * f2;
        f3 = di * (a3 + s3 * di) + bv.w; f3 = f3 >= 0.f ? f3 : av.w * f3;
    }
    if (slot >= 8)
        *(float4*)&fs[(slot - 8) * 64 + (g << 2)] = make_float4(f0, f1, f2, f3);
    __syncthreads();
    if (slot < 8 && active) {
        float4 p = *(const float4*)&fs[slot * 64 + (g << 2)];
        ((float4*)out)[j * 16 + g] = make_float4(0.5f * (f0 + p.x), 0.5f * (f1 + p.y),
                                                 0.5f * (f2 + p.z), 0.5f * (f3 + p.w));
    }
}

extern "C" void kernel_launch(void* const* d_in, const int* in_sizes, int n_in,
                              void* d_out, int out_size, void* d_ws, size_t ws_size,
                              hipStream_t stream) {
    const float* x  = (const float*)d_in[0];
    const int*   ei = (const int*)d_in[1];
    const float* ew = (const float*)d_in[2];
    const int*   et = (const int*)d_in[3];
    const float* W1 = (const float*)d_in[4];
    const float* b1 = (const float*)d_in[5];
    const float* a1 = (const float*)d_in[6];
    const float* W2 = (const float*)d_in[7];
    const float* b2 = (const float*)d_in[8];
    const float* a2 = (const float*)d_in[9];

    const int N = in_sizes[0] / 128;   // 100000
    const int E = in_sizes[1] / 2;     // 1600000
    const int* src = ei;
    const int* dst = ei + E;

    // Workspace (4-byte words), ~91 MB:
    //   dinv1 N | dinv2 N | xb1 64N | xb2 32N | cnt N | ell 128N
    float*    ws    = (float*)d_ws;
    float*    dinv1 = ws;
    float*    dinv2 = dinv1 + N;
    unsigned* xb1   = (unsigned*)(dinv2 + N);
    unsigned* xb2   = xb1 + (size_t)N * 64;
    int*      cnt   = (int*)(xb2 + (size_t)N * 32);
    int2*     ell   = (int2*)(cnt + N);

    const int G_ell = (E + 2047) / 2048;           // 782 (8 edges/thread)
    const int G_gemm = (N + 31) / 32;              // 3125

    hipMemsetAsync(cnt, 0, (size_t)N * sizeof(int), stream);

    k_ell_gemm1<<<G_ell + G_gemm, 256, 0, stream>>>(
        src, dst, et, ew, cnt, ell, E, x, W1, xb1, N, G_ell);

    k_dinv<<<(N + 15) / 16, 256, 0, stream>>>(cnt, ell, dinv1, dinv2, N);

    k_g1g2<<<(N + 7) / 8, 256, 0, stream>>>(cnt, ell, xb1, dinv1, b1, a1,
                                            W2, xb2, N);

    k_g2h<<<(N / 2 + 7) / 8, 256, 0, stream>>>(cnt, ell, xb2, dinv2, b2, a2,
                                               (float*)d_out, N / 2);
}

// Round 2
// 387.536 us; speedup vs baseline: 1.0983x; 1.0983x over previous
//
#include <hip/hip_runtime.h>

// ---------------------------------------------------------------------------
// DoubleLayeredEncoder: 2-layer GCN + PReLU + half-sum. N=100k, E=1.6M.
// R7: split k_ell_gemm1 for attribution + make gemm1 MFMA-based.
//  - k_prep: zero cnt + pack W1 -> transposed [col][k] bf16 hi/lo (64KB)
//    in workspace (replaces memset; hi/lo split => ~fp32 accuracy).
//  - k_ell: standalone ELL build, 4 edges/thread, no LDS, full occupancy.
//  - k_gemm1: MFMA 16x16x32_bf16, 3-term hi/lo (x and W), W staged in
//    64KB LDS (XOR-swizzled, conflict-free b128 frag reads). Each wave:
//    16 rows x 128 cols. x loaded global->regs directly.
// Pipeline: k_prep -> k_ell -> k_gemm1 -> k_dinv -> k_g1g2 -> k_g2h
// ---------------------------------------------------------------------------

#define ELL_CAP 64

typedef short short8 __attribute__((ext_vector_type(8)));
typedef float f32x4 __attribute__((ext_vector_type(4)));

__device__ __forceinline__ unsigned bf16rne(float x) {
    unsigned u = __float_as_uint(x);
    return (u + 0x7FFFu + ((u >> 16) & 1u)) >> 16;
}
__device__ __forceinline__ unsigned pack2bf(float a, float b) {
    return bf16rne(a) | (bf16rne(b) << 16);
}
// split (a,b) into packed bf16 hi pair and bf16 lo (residual) pair
__device__ __forceinline__ void hilo2(float a, float b, unsigned& h, unsigned& l) {
    unsigned ha = bf16rne(a), hb = bf16rne(b);
    float la = a - __uint_as_float(ha << 16);
    float lb = b - __uint_as_float(hb << 16);
    h = ha | (hb << 16);
    l = bf16rne(la) | (bf16rne(lb) << 16);
}

// ---- prep: blocks [0,32) pack W1 -> Wt hi/lo; blocks [32,..) zero cnt ------
__global__ __launch_bounds__(256) void k_prep(const float* __restrict__ W,
                                              unsigned* __restrict__ wt_hi,
                                              unsigned* __restrict__ wt_lo,
                                              int* __restrict__ cnt, int n) {
    int t = threadIdx.x;
    if ((int)blockIdx.x < 32) {
        int idx = blockIdx.x * 256 + t;   // 0..8191 (u32 slots, [c][k-pair])
        int c = idx >> 6;
        int kp = idx & 63;
        float w0 = W[(2 * kp) * 128 + c];
        float w1 = W[(2 * kp + 1) * 128 + c];
        unsigned h, l;
        hilo2(w0, w1, h, l);
        wt_hi[idx] = h;
        wt_lo[idx] = l;
    } else {
        int i = ((int)blockIdx.x - 32) * 256 + t;
        if (i < n) cnt[i] = 0;
    }
}

// ---- ELL build: 4 edges/thread, standalone (full occupancy, no LDS) --------
__global__ __launch_bounds__(256) void k_ell(
    const int* __restrict__ src, const int* __restrict__ dst,
    const int* __restrict__ et, const float* __restrict__ ew,
    int* __restrict__ cnt, int2* __restrict__ ell, int E) {
    int e0 = (blockIdx.x * 256 + threadIdx.x) * 4;
    if (e0 + 4 <= E) {
        int4 s4 = *(const int4*)(src + e0);
        int4 d4 = *(const int4*)(dst + e0);
        int4 t4 = *(const int4*)(et + e0);
        float4 w4 = *(const float4*)(ew + e0);
        int s[4] = {s4.x, s4.y, s4.z, s4.w};
        int d[4] = {d4.x, d4.y, d4.z, d4.w};
        int tt[4] = {t4.x, t4.y, t4.z, t4.w};
        float w[4] = {w4.x, w4.y, w4.z, w4.w};
        int p[4];
#pragma unroll
        for (int i = 0; i < 4; i++) p[i] = atomicAdd(&cnt[d[i]], 1);
#pragma unroll
        for (int i = 0; i < 4; i++)
            if (p[i] < ELL_CAP)
                ell[d[i] * ELL_CAP + p[i]] =
                    make_int2(s[i] | (tt[i] << 24), __float_as_int(w[i]));
    } else if (e0 < E) {
        for (int i = 0; i < E - e0; i++) {
            int di = dst[e0 + i];
            int p = atomicAdd(&cnt[di], 1);
            if (p < ELL_CAP)
                ell[di * ELL_CAP + p] =
                    make_int2(src[e0 + i] | (et[e0 + i] << 24),
                              __float_as_int(ew[e0 + i]));
        }
    }
}

// ---- gemm1: xb1 = bf16(x @ W1) via MFMA, hi/lo 3-term (~fp32 accurate) -----
// Block 256 = 4 waves, 64 rows/block (16/wave). Wt hi/lo in LDS (64KB),
// swizzle: byte ^= (col&7)<<4 -> conflict-free ds_read_b128 B-fragments.
__global__ __launch_bounds__(256) void k_gemm1(
    const float* __restrict__ x,
    const unsigned* __restrict__ wt_hi, const unsigned* __restrict__ wt_lo,
    unsigned short* __restrict__ xb1, int n) {
    __shared__ __align__(16) char lds[65536];   // hi @0, lo @32768
    int t = threadIdx.x;

    // stage Wt: 64 lanes cover one [c] row of 64 u32 per instr -> same swizzle
    // constant -> contiguous -> conflict-free.
#pragma unroll 8
    for (int i = 0; i < 32; i++) {
        int idx = t + 256 * i;                       // 0..8191
        unsigned byte = (unsigned)(idx * 4) ^ ((((unsigned)idx >> 6) & 7u) << 4);
        *(unsigned*)(lds + byte) = wt_hi[idx];
        *(unsigned*)(lds + 32768 + byte) = wt_lo[idx];
    }
    __syncthreads();

    int l = t & 63, wv = t >> 6;
    int lrow = l & 15, lk = l >> 4;                  // frag row / k-group
    int r0 = (int)blockIdx.x * 64 + wv * 16;
    int row = r0 + lrow;
    bool rok = row < n;
    const float* xbase = x + (size_t)row * 128 + lk * 8;

    f32x4 acc[8];
#pragma unroll
    for (int i = 0; i < 8; i++) acc[i] = (f32x4){0.f, 0.f, 0.f, 0.f};

#pragma unroll
    for (int s = 0; s < 4; s++) {
        float4 v0 = make_float4(0.f, 0.f, 0.f, 0.f);
        float4 v1 = make_float4(0.f, 0.f, 0.f, 0.f);
        if (rok) {
            v0 = *(const float4*)(xbase + s * 32);
            v1 = *(const float4*)(xbase + s * 32 + 4);
        }
        union { short8 v; unsigned u[4]; } Ah, Al;
        hilo2(v0.x, v0.y, Ah.u[0], Al.u[0]);
        hilo2(v0.z, v0.w, Ah.u[1], Al.u[1]);
        hilo2(v1.x, v1.y, Ah.u[2], Al.u[2]);
        hilo2(v1.z, v1.w, Ah.u[3], Al.u[3]);
#pragma unroll
        for (int ct = 0; ct < 8; ct++) {
            int col = ct * 16 + lrow;
            unsigned byte = ((unsigned)(col << 8) + (unsigned)(s << 6) +
                             (unsigned)(lk << 4)) ^ (((unsigned)col & 7u) << 4);
            short8 bh = *(const short8*)(lds + byte);
            short8 bl = *(const short8*)(lds + 32768 + byte);
            acc[ct] = __builtin_amdgcn_mfma_f32_16x16x32_bf16(Ah.v, bh, acc[ct], 0, 0, 0);
            acc[ct] = __builtin_amdgcn_mfma_f32_16x16x32_bf16(Al.v, bh, acc[ct], 0, 0, 0);
            acc[ct] = __builtin_amdgcn_mfma_f32_16x16x32_bf16(Ah.v, bl, acc[ct], 0, 0, 0);
        }
    }

    // C/D layout: col = lane&15, row = (lane>>4)*4 + q
#pragma unroll
    for (int q = 0; q < 4; q++) {
        int orow = r0 + lk * 4 + q;
        if (orow < n) {
#pragma unroll
            for (int ct = 0; ct < 8; ct++)
                xb1[(size_t)orow * 128 + ct * 16 + lrow] =
                    (unsigned short)bf16rne(acc[ct][q]);
        }
    }
}

// ---- weighted degrees + rsqrt, wave-cooperative (coalesced row reads) ------
__global__ __launch_bounds__(256) void k_dinv(const int* __restrict__ cnt,
                                              const int2* __restrict__ ell,
                                              float* __restrict__ dinv1,
                                              float* __restrict__ dinv2, int n) {
    int t = threadIdx.x;
    int d = blockIdx.x * 16 + (t >> 4);
    int g = t & 15;
    float s1 = 0.f, s2 = 0.f;
    if (d < n) {
        int len = min(cnt[d], ELL_CAP);
        const int2* row = ell + (size_t)d * ELL_CAP;
        for (int kk = g; kk < len; kk += 16) {
            int2 e = row[kk];
            s1 += __int_as_float(e.y);
            s2 += (float)(((unsigned)e.x) >> 24);
        }
    }
#pragma unroll
    for (int o = 8; o >= 1; o >>= 1) {
        s1 += __shfl_xor(s1, o, 16);
        s2 += __shfl_xor(s2, o, 16);
    }
    if (d < n && g == 0) {
        dinv1[d] = rsqrtf(1.0f + s1);
        dinv2[d] = rsqrtf(1.0f + s2);
    }
}

// ---- gather layer 1 (+dinv, bias, PReLU) fused with gemm2 -> xb2 -----------
__global__ __launch_bounds__(256) void k_g1g2(const int* __restrict__ cnt,
                                              const int2* __restrict__ ell,
                                              const unsigned* __restrict__ xb1,
                                              const float* __restrict__ dinv1,
                                              const float* __restrict__ b,
                                              const float* __restrict__ alpha,
                                              const float* __restrict__ W2,
                                              unsigned* __restrict__ xb2, int n) {
    __shared__ unsigned W2s[128 * 32];   // bf16-packed pairs of cols, 16 KB
    __shared__ float hs[8 * 128];        // h1 tile, 4 KB
    int t = threadIdx.x;

    const float2* W22 = (const float2*)W2;
#pragma unroll
    for (int i = 0; i < 16; i++) {
        int idx = t + 256 * i;           // 0..4095
        float2 v = W22[idx];
        W2s[idx] = pack2bf(v.x, v.y);
    }

    int nl = t >> 5;                     // node slot 0..7
    int g = t & 31;
    int d = blockIdx.x * 8 + nl;
    bool active = d < n;
    int len = active ? min(cnt[d], ELL_CAP) : 0;
    const int2* row = ell + (size_t)d * ELL_CAP;
    const uint2* x2 = (const uint2*)xb1;

    float a0 = 0.f, a1v_ = 0.f, a2v_ = 0.f, a3 = 0.f;
    for (int k0 = 0; k0 < len; k0 += 32) {
        int kk = k0 + g;
        int2 ent = (kk < len) ? row[kk] : make_int2(0, 0);
        float cf = 0.f;
        if (kk < len) cf = __int_as_float(ent.y) * dinv1[ent.x & 0xFFFFFF];
        int m = min(32, len - k0);
        for (int j = 0; j < m; j++) {
            int pej = __shfl(ent.x, j, 32);
            float cj = __shfl(cf, j, 32);
            int s = pej & 0xFFFFFF;
            uint2 q = x2[s * 32 + g];
            a0 += __uint_as_float(q.x << 16) * cj;
            a1v_ += __uint_as_float(q.x & 0xFFFF0000u) * cj;
            a2v_ += __uint_as_float(q.y << 16) * cj;
            a3 += __uint_as_float(q.y & 0xFFFF0000u) * cj;
        }
    }

    if (active) {
        float di = dinv1[d];
        uint2 sq = x2[d * 32 + g];
        float s0 = __uint_as_float(sq.x << 16);
        float s1 = __uint_as_float(sq.x & 0xFFFF0000u);
        float s2 = __uint_as_float(sq.y << 16);
        float s3 = __uint_as_float(sq.y & 0xFFFF0000u);
        int c4 = g << 2;
        float4 bv = *(const float4*)&b[c4];
        float4 av = *(const float4*)&alpha[c4];
        float v0 = di * (a0 + s0 * di) + bv.x; v0 = v0 >= 0.f ? v0 : av.x * v0;
        float v1 = di * (a1v_ + s1 * di) + bv.y; v1 = v1 >= 0.f ? v1 : av.y * v1;
        float v2 = di * (a2v_ + s2 * di) + bv.z; v2 = v2 >= 0.f ? v2 : av.z * v2;
        float v3 = di * (a3 + s3 * di) + bv.w; v3 = v3 >= 0.f ? v3 : av.w * v3;
        *(float4*)&hs[nl * 128 + c4] = make_float4(v0, v1, v2, v3);
    }
    __syncthreads();

    float o0 = 0.f, o1 = 0.f;
#pragma unroll 4
    for (int k = 0; k < 128; k++) {
        float hv = hs[nl * 128 + k];
        unsigned pw = W2s[k * 32 + g];
        o0 += hv * __uint_as_float(pw << 16);
        o1 += hv * __uint_as_float(pw & 0xFFFF0000u);
    }
    if (active) xb2[d * 32 + g] = pack2bf(o0, o1);
}

// ---- gather layer 2 (+dinv, bias, PReLU) fused with half-sum readout -------
__global__ __launch_bounds__(256) void k_g2h(const int* __restrict__ cnt,
                                             const int2* __restrict__ ell,
                                             const unsigned* __restrict__ xb2,
                                             const float* __restrict__ dinv2,
                                             const float* __restrict__ b,
                                             const float* __restrict__ alpha,
                                             float* __restrict__ out, int half) {
    __shared__ float fs[8 * 64];         // second-half results, 2 KB
    int t = threadIdx.x;
    int slot = t >> 4;                   // 0..15
    int g = t & 15;
    int base = blockIdx.x * 8;
    int j = base + ((slot < 8) ? slot : (slot - 8));
    int d = (slot < 8) ? j : (j + half);
    bool active = j < half;
    int len = active ? min(cnt[d], ELL_CAP) : 0;
    const int2* row = ell + (size_t)d * ELL_CAP;
    const uint2* x2 = (const uint2*)xb2;

    float a0 = 0.f, a1v_ = 0.f, a2v_ = 0.f, a3 = 0.f;
    for (int k0 = 0; k0 < len; k0 += 16) {
        int kk = k0 + g;
        int2 ent = (kk < len) ? row[kk] : make_int2(0, 0);
        float cf = 0.f;
        if (kk < len) {
            int tt = ((unsigned)ent.x) >> 24;
            if (tt) cf = (float)tt * dinv2[ent.x & 0xFFFFFF];
        }
        int m = min(16, len - k0);
        for (int jj = 0; jj < m; jj++) {
            int pej = __shfl(ent.x, jj, 16);
            float cj = __shfl(cf, jj, 16);
            if (cj != 0.f) {
                int s = pej & 0xFFFFFF;
                uint2 q = x2[s * 16 + g];
                a0 += __uint_as_float(q.x << 16) * cj;
                a1v_ += __uint_as_float(q.x & 0xFFFF0000u) * cj;
                a2v_ += __uint_as_float(q.y << 16) * cj;
                a3 += __uint_as_float(q.y & 0xFFFF0000u) * cj;
            }
        }
    }

    float f0 = 0.f, f1 = 0.f, f2 = 0.f, f3 = 0.f;
    if (active) {
        float di = dinv2[d];
        uint2 sq = x2[d * 16 + g];
        float s0 = __uint_as_float(sq.x << 16);
        float s1 = __uint_as_float(sq.x & 0xFFFF0000u);
        float s2 = __uint_as_float(sq.y << 16);
        float s3 = __uint_as_float(sq.y & 0xFFFF0000u);
        int c4 = g << 2;
        float4 bv = *(const float4*)&b[c4];
        float4 av = *(const float4*)&alpha[c4];
        f0 = di * (a0 + s0 * di) + bv.x; f0 = f0 >= 0.f ? f0 : av.x * f0;
        f1 = di * (a1v_ + s1 * di) + bv.y; f1 = f1 >= 0.f ? f1 : av.y * f1;
        f2 = di * (a2v_ + s2 * di) + bv.z; f2 = f2 >= 0.f ? f2 : av.z * f2;
        f3 = di * (a3 + s3 * di) + bv.w; f3 = f3 >= 0.f ? f3 : av.w * f3;
    }
    if (slot >= 8)
        *(float4*)&fs[(slot - 8) * 64 + (g << 2)] = make_float4(f0, f1, f2, f3);
    __syncthreads();
    if (slot < 8 && active) {
        float4 p = *(const float4*)&fs[slot * 64 + (g << 2)];
        ((float4*)out)[j * 16 + g] = make_float4(0.5f * (f0 + p.x), 0.5f * (f1 + p.y),
                                                 0.5f * (f2 + p.z), 0.5f * (f3 + p.w));
    }
}

extern "C" void kernel_launch(void* const* d_in, const int* in_sizes, int n_in,
                              void* d_out, int out_size, void* d_ws, size_t ws_size,
                              hipStream_t stream) {
    const float* x  = (const float*)d_in[0];
    const int*   ei = (const int*)d_in[1];
    const float* ew = (const float*)d_in[2];
    const int*   et = (const int*)d_in[3];
    const float* W1 = (const float*)d_in[4];
    const float* b1 = (const float*)d_in[5];
    const float* a1 = (const float*)d_in[6];
    const float* W2 = (const float*)d_in[7];
    const float* b2 = (const float*)d_in[8];
    const float* a2 = (const float*)d_in[9];

    const int N = in_sizes[0] / 128;   // 100000
    const int E = in_sizes[1] / 2;     // 1600000
    const int* src = ei;
    const int* dst = ei + E;

    // Workspace (4-byte words), ~91 MB (+64KB Wt):
    //   dinv1 N | dinv2 N | xb1 64N | xb2 32N | cnt N | ell 128N | wt 16K
    float*    ws    = (float*)d_ws;
    float*    dinv1 = ws;
    float*    dinv2 = dinv1 + N;
    unsigned* xb1   = (unsigned*)(dinv2 + N);
    unsigned* xb2   = xb1 + (size_t)N * 64;
    int*      cnt   = (int*)(xb2 + (size_t)N * 32);
    int2*     ell   = (int2*)(cnt + N);
    unsigned* wt_hi = (unsigned*)(ell + (size_t)N * ELL_CAP);
    unsigned* wt_lo = wt_hi + 8192;

    k_prep<<<32 + (N + 255) / 256, 256, 0, stream>>>(W1, wt_hi, wt_lo, cnt, N);

    k_ell<<<(E / 4 + 255) / 256, 256, 0, stream>>>(src, dst, et, ew, cnt, ell, E);

    k_gemm1<<<(N + 63) / 64, 256, 0, stream>>>(x, wt_hi, wt_lo,
                                               (unsigned short*)xb1, N);

    k_dinv<<<(N + 15) / 16, 256, 0, stream>>>(cnt, ell, dinv1, dinv2, N);

    k_g1g2<<<(N + 7) / 8, 256, 0, stream>>>(cnt, ell, xb1, dinv1, b1, a1,
                                            W2, xb2, N);

    k_g2h<<<(N / 2 + 7) / 8, 256, 0, stream>>>(cnt, ell, xb2, dinv2, b2, a2,
                                               (float*)d_out, N / 2);
}

// Round 3
// 363.365 us; speedup vs baseline: 1.1713x; 1.0665x over previous
//
#include <hip/hip_runtime.h>

// ---------------------------------------------------------------------------
// DoubleLayeredEncoder: 2-layer GCN + PReLU + half-sum. N=100k, E=1.6M.
// R8:
//  - k_prep: zero cnt + pre-fragment W1 (hi/lo bf16 B-frags, 64KB) and
//    W2 (bf16 B-frags, 16KB) in MFMA operand order.
//  - k_ellgemm: heterogeneous fusion. ELL blocks (atomic scatter, idle VALU)
//    co-resident with gemm1 blocks (MFMA, B-frags straight from L2, NO LDS
//    so ELL keeps 8 blocks/CU). gemm1 hides under ELL's 125us latency wall.
//  - k_g1g2: 16 nodes/block, 16 lanes/node gather; gemm2 tail now MFMA
//    (h1 as hi/lo bf16 A-frags in swizzled LDS x W2 B-frags) -- kills the
//    640-instr/wave VALU tail and 3/4 of the per-block W2 traffic.
// Pipeline: k_prep -> k_ellgemm -> k_dinv -> k_g1g2 -> k_g2h
// ---------------------------------------------------------------------------

#define ELL_CAP 64

typedef short short8 __attribute__((ext_vector_type(8)));
typedef float f32x4 __attribute__((ext_vector_type(4)));

__device__ __forceinline__ unsigned bf16rne(float x) {
    unsigned u = __float_as_uint(x);
    return (u + 0x7FFFu + ((u >> 16) & 1u)) >> 16;
}
__device__ __forceinline__ unsigned pack2bf(float a, float b) {
    return bf16rne(a) | (bf16rne(b) << 16);
}
// split (a,b) into packed bf16 hi pair and bf16 lo (residual) pair
__device__ __forceinline__ void hilo2(float a, float b, unsigned& h, unsigned& l) {
    unsigned ha = bf16rne(a), hb = bf16rne(b);
    float la = a - __uint_as_float(ha << 16);
    float lb = b - __uint_as_float(hb << 16);
    h = ha | (hb << 16);
    l = bf16rne(la) | (bf16rne(lb) << 16);
}
__device__ __forceinline__ float bflo(unsigned u) { return __uint_as_float(u << 16); }
__device__ __forceinline__ float bfhi(unsigned u) { return __uint_as_float(u & 0xFFFF0000u); }

// ---- prep: W1 -> hi/lo B-frags; W2 -> bf16 B-frags; zero cnt ---------------
// B-frag order (convention, consistent across A and B so any true HW k-perm
// cancels): lane l -> col = ct*16 + (l&15), k = s*32 + (l>>4)*8 + 2r + {0,1}.
// Array: frag[((ct*NS + s)*64 + l)*4 + r]
__global__ __launch_bounds__(256) void k_prep(const float* __restrict__ W1,
                                              const float* __restrict__ W2,
                                              unsigned* __restrict__ w1p_hi,
                                              unsigned* __restrict__ w1p_lo,
                                              unsigned* __restrict__ w2p,
                                              int* __restrict__ cnt, int n) {
    int t = threadIdx.x;
    int bx = blockIdx.x;
    if (bx < 32) {                        // W1: 8192 u32-slots, ct in [0,8)
        int idx = bx * 256 + t;
        int r = idx & 3, l = (idx >> 2) & 63, sct = idx >> 8;
        int s = sct & 3, ct = sct >> 2;
        int col = ct * 16 + (l & 15);
        int k0 = s * 32 + (l >> 4) * 8 + 2 * r;
        unsigned h, lo;
        hilo2(W1[k0 * 128 + col], W1[(k0 + 1) * 128 + col], h, lo);
        w1p_hi[idx] = h;
        w1p_lo[idx] = lo;
    } else if (bx < 48) {                 // W2: 4096 u32-slots, ct in [0,4)
        int idx = (bx - 32) * 256 + t;
        int r = idx & 3, l = (idx >> 2) & 63, sct = idx >> 8;
        int s = sct & 3, ct = sct >> 2;
        int col = ct * 16 + (l & 15);
        int k0 = s * 32 + (l >> 4) * 8 + 2 * r;
        w2p[idx] = pack2bf(W2[k0 * 64 + col], W2[(k0 + 1) * 64 + col]);
    } else {
        int i = (bx - 48) * 256 + t;
        if (i < n) cnt[i] = 0;
    }
}

// ---- fused: blocks [0,G_ell) build ELL; rest do MFMA gemm1 (no LDS) --------
__global__ __launch_bounds__(256) void k_ellgemm(
    const int* __restrict__ src, const int* __restrict__ dst,
    const int* __restrict__ et, const float* __restrict__ ew,
    int* __restrict__ cnt, int2* __restrict__ ell, int E,
    const float* __restrict__ x,
    const unsigned* __restrict__ w1p_hi, const unsigned* __restrict__ w1p_lo,
    unsigned short* __restrict__ xb1, int n, int G_ell) {
    int t = threadIdx.x;

    if ((int)blockIdx.x < G_ell) {
        // ---- ELL build: 4 edges/thread ----
        int e0 = (blockIdx.x * 256 + t) * 4;
        if (e0 + 4 <= E) {
            int4 s4 = *(const int4*)(src + e0);
            int4 d4 = *(const int4*)(dst + e0);
            int4 t4 = *(const int4*)(et + e0);
            float4 w4 = *(const float4*)(ew + e0);
            int s[4] = {s4.x, s4.y, s4.z, s4.w};
            int d[4] = {d4.x, d4.y, d4.z, d4.w};
            int tt[4] = {t4.x, t4.y, t4.z, t4.w};
            float w[4] = {w4.x, w4.y, w4.z, w4.w};
            int p[4];
#pragma unroll
            for (int i = 0; i < 4; i++) p[i] = atomicAdd(&cnt[d[i]], 1);
#pragma unroll
            for (int i = 0; i < 4; i++)
                if (p[i] < ELL_CAP)
                    ell[d[i] * ELL_CAP + p[i]] =
                        make_int2(s[i] | (tt[i] << 24), __float_as_int(w[i]));
        } else if (e0 < E) {
            for (int i = 0; i < E - e0; i++) {
                int di = dst[e0 + i];
                int p = atomicAdd(&cnt[di], 1);
                if (p < ELL_CAP)
                    ell[di * ELL_CAP + p] =
                        make_int2(src[e0 + i] | (et[e0 + i] << 24),
                                  __float_as_int(ew[e0 + i]));
            }
        }
        return;
    }

    // ---- gemm1: 64 rows/block (16/wave), B-frags from L2, no LDS ----
    int l = t & 63, wv = t >> 6;
    int lrow = l & 15, lk = l >> 4;
    int r0 = ((int)blockIdx.x - G_ell) * 64 + wv * 16;
    int row = r0 + lrow;
    bool rok = row < n;
    const float* xbase = x + (size_t)row * 128 + lk * 8;

    f32x4 acc[8];
#pragma unroll
    for (int i = 0; i < 8; i++) acc[i] = (f32x4){0.f, 0.f, 0.f, 0.f};

#pragma unroll
    for (int s = 0; s < 4; s++) {
        float4 v0 = make_float4(0.f, 0.f, 0.f, 0.f);
        float4 v1 = make_float4(0.f, 0.f, 0.f, 0.f);
        if (rok) {
            v0 = *(const float4*)(xbase + s * 32);
            v1 = *(const float4*)(xbase + s * 32 + 4);
        }
        union { short8 v; unsigned u[4]; } Ah, Al;
        hilo2(v0.x, v0.y, Ah.u[0], Al.u[0]);
        hilo2(v0.z, v0.w, Ah.u[1], Al.u[1]);
        hilo2(v1.x, v1.y, Ah.u[2], Al.u[2]);
        hilo2(v1.z, v1.w, Ah.u[3], Al.u[3]);
#pragma unroll
        for (int ct = 0; ct < 8; ct++) {
            int off = ((ct * 4 + s) * 64 + l) * 4;
            short8 bh = *(const short8*)(w1p_hi + off);
            short8 bl = *(const short8*)(w1p_lo + off);
            acc[ct] = __builtin_amdgcn_mfma_f32_16x16x32_bf16(Ah.v, bh, acc[ct], 0, 0, 0);
            acc[ct] = __builtin_amdgcn_mfma_f32_16x16x32_bf16(Al.v, bh, acc[ct], 0, 0, 0);
            acc[ct] = __builtin_amdgcn_mfma_f32_16x16x32_bf16(Ah.v, bl, acc[ct], 0, 0, 0);
        }
    }

    // C/D: col = lane&15, row = (lane>>4)*4 + q
#pragma unroll
    for (int q = 0; q < 4; q++) {
        int orow = r0 + lk * 4 + q;
        if (orow < n) {
#pragma unroll
            for (int ct = 0; ct < 8; ct++)
                xb1[(size_t)orow * 128 + ct * 16 + lrow] =
                    (unsigned short)bf16rne(acc[ct][q]);
        }
    }
}

// ---- weighted degrees + rsqrt ----------------------------------------------
__global__ __launch_bounds__(256) void k_dinv(const int* __restrict__ cnt,
                                              const int2* __restrict__ ell,
                                              float* __restrict__ dinv1,
                                              float* __restrict__ dinv2, int n) {
    int t = threadIdx.x;
    int d = blockIdx.x * 16 + (t >> 4);
    int g = t & 15;
    float s1 = 0.f, s2 = 0.f;
    if (d < n) {
        int len = min(cnt[d], ELL_CAP);
        const int2* row = ell + (size_t)d * ELL_CAP;
        for (int kk = g; kk < len; kk += 16) {
            int2 e = row[kk];
            s1 += __int_as_float(e.y);
            s2 += (float)(((unsigned)e.x) >> 24);
        }
    }
#pragma unroll
    for (int o = 8; o >= 1; o >>= 1) {
        s1 += __shfl_xor(s1, o, 16);
        s2 += __shfl_xor(s2, o, 16);
    }
    if (d < n && g == 0) {
        dinv1[d] = rsqrtf(1.0f + s1);
        dinv2[d] = rsqrtf(1.0f + s2);
    }
}

// ---- gather layer 1 (+dinv, bias, PReLU) + MFMA gemm2 -> xb2 ---------------
// 16 nodes/block, 16 lanes/node (8 ch/lane). h1 -> hi/lo bf16 A-frags in
// XOR-swizzled LDS; gemm2 = 8 MFMAs/wave vs W2 B-frags from L2.
__global__ __launch_bounds__(256) void k_g1g2(const int* __restrict__ cnt,
                                              const int2* __restrict__ ell,
                                              const unsigned* __restrict__ xb1,
                                              const float* __restrict__ dinv1,
                                              const float* __restrict__ b,
                                              const float* __restrict__ alpha,
                                              const unsigned* __restrict__ w2p,
                                              unsigned short* __restrict__ xb2,
                                              int n) {
    __shared__ __align__(16) unsigned hsh[16 * 64];   // h1 hi kpairs, 4KB
    __shared__ __align__(16) unsigned hsl[16 * 64];   // h1 lo kpairs, 4KB
    int t = threadIdx.x;
    int nl = t >> 4;                     // node slot 0..15
    int g = t & 15;                      // 8 channels: [8g, 8g+8)
    int d = blockIdx.x * 16 + nl;
    bool active = d < n;
    int len = active ? min(cnt[d], ELL_CAP) : 0;
    const int2* row = ell + (size_t)d * ELL_CAP;
    const uint4* x4 = (const uint4*)xb1;  // [N][16] uint4

    float a[8] = {0.f, 0.f, 0.f, 0.f, 0.f, 0.f, 0.f, 0.f};
    for (int k0 = 0; k0 < len; k0 += 16) {
        int kk = k0 + g;
        int2 ent = (kk < len) ? row[kk] : make_int2(0, 0);
        float cf = 0.f;
        if (kk < len) cf = __int_as_float(ent.y) * dinv1[ent.x & 0xFFFFFF];
        int m = min(16, len - k0);
        for (int j = 0; j < m; j++) {
            int pej = __shfl(ent.x, j, 16);
            float cj = __shfl(cf, j, 16);
            int s = pej & 0xFFFFFF;
            uint4 q = x4[s * 16 + g];
            a[0] += bflo(q.x) * cj; a[1] += bfhi(q.x) * cj;
            a[2] += bflo(q.y) * cj; a[3] += bfhi(q.y) * cj;
            a[4] += bflo(q.z) * cj; a[5] += bfhi(q.z) * cj;
            a[6] += bflo(q.w) * cj; a[7] += bfhi(q.w) * cj;
        }
    }

    if (active) {
        float di = dinv1[d];
        uint4 sq = x4[d * 16 + g];
        float sv[8] = {bflo(sq.x), bfhi(sq.x), bflo(sq.y), bfhi(sq.y),
                       bflo(sq.z), bfhi(sq.z), bflo(sq.w), bfhi(sq.w)};
        int c8 = g << 3;
        float4 b0 = *(const float4*)&b[c8];
        float4 b1v = *(const float4*)&b[c8 + 4];
        float4 av0 = *(const float4*)&alpha[c8];
        float4 av1 = *(const float4*)&alpha[c8 + 4];
        float bb[8] = {b0.x, b0.y, b0.z, b0.w, b1v.x, b1v.y, b1v.z, b1v.w};
        float aa[8] = {av0.x, av0.y, av0.z, av0.w, av1.x, av1.y, av1.z, av1.w};
        float v[8];
#pragma unroll
        for (int i = 0; i < 8; i++) {
            float vv = di * (a[i] + sv[i] * di) + bb[i];
            v[i] = vv >= 0.f ? vv : aa[i] * vv;
        }
        unsigned H[4], L[4];
        hilo2(v[0], v[1], H[0], L[0]);
        hilo2(v[2], v[3], H[1], L[1]);
        hilo2(v[4], v[5], H[2], L[2]);
        hilo2(v[6], v[7], H[3], L[3]);
        unsigned byte = ((unsigned)(nl * 256 + g * 16)) ^ (((unsigned)nl & 7u) << 4);
        *(uint4*)((char*)hsh + byte) = make_uint4(H[0], H[1], H[2], H[3]);
        *(uint4*)((char*)hsl + byte) = make_uint4(L[0], L[1], L[2], L[3]);
    }
    __syncthreads();

    // gemm2: wave w -> col tile ct=w (cols 16w..16w+15), rows = 16 nodes
    int l = t & 63, w = t >> 6;
    int arow = l & 15, kg = l >> 4;
    f32x4 acc = (f32x4){0.f, 0.f, 0.f, 0.f};
#pragma unroll
    for (int s = 0; s < 4; s++) {
        unsigned byte = ((unsigned)(arow * 256 + s * 64 + kg * 16)) ^
                        (((unsigned)arow & 7u) << 4);
        short8 Ah = *(const short8*)((char*)hsh + byte);
        short8 Al = *(const short8*)((char*)hsl + byte);
        short8 B = *(const short8*)(w2p + ((w * 4 + s) * 64 + l) * 4);
        acc = __builtin_amdgcn_mfma_f32_16x16x32_bf16(Ah, B, acc, 0, 0, 0);
        acc = __builtin_amdgcn_mfma_f32_16x16x32_bf16(Al, B, acc, 0, 0, 0);
    }
    int col = w * 16 + arow;
#pragma unroll
    for (int q = 0; q < 4; q++) {
        int node = blockIdx.x * 16 + kg * 4 + q;
        if (node < n)
            xb2[(size_t)node * 64 + col] = (unsigned short)bf16rne(acc[q]);
    }
}

// ---- gather layer 2 (+dinv, bias, PReLU) fused with half-sum readout -------
__global__ __launch_bounds__(256) void k_g2h(const int* __restrict__ cnt,
                                             const int2* __restrict__ ell,
                                             const unsigned* __restrict__ xb2,
                                             const float* __restrict__ dinv2,
                                             const float* __restrict__ b,
                                             const float* __restrict__ alpha,
                                             float* __restrict__ out, int half) {
    __shared__ float fs[8 * 64];         // second-half results, 2 KB
    int t = threadIdx.x;
    int slot = t >> 4;                   // 0..15
    int g = t & 15;
    int base = blockIdx.x * 8;
    int j = base + ((slot < 8) ? slot : (slot - 8));
    int d = (slot < 8) ? j : (j + half);
    bool active = j < half;
    int len = active ? min(cnt[d], ELL_CAP) : 0;
    const int2* row = ell + (size_t)d * ELL_CAP;
    const uint2* x2 = (const uint2*)xb2;

    float a0 = 0.f, a1v_ = 0.f, a2v_ = 0.f, a3 = 0.f;
    for (int k0 = 0; k0 < len; k0 += 16) {
        int kk = k0 + g;
        int2 ent = (kk < len) ? row[kk] : make_int2(0, 0);
        float cf = 0.f;
        if (kk < len) {
            int tt = ((unsigned)ent.x) >> 24;
            if (tt) cf = (float)tt * dinv2[ent.x & 0xFFFFFF];
        }
        int m = min(16, len - k0);
        for (int jj = 0; jj < m; jj++) {
            int pej = __shfl(ent.x, jj, 16);
            float cj = __shfl(cf, jj, 16);
            if (cj != 0.f) {
                int s = pej & 0xFFFFFF;
                uint2 q = x2[s * 16 + g];
                a0 += bflo(q.x) * cj;
                a1v_ += bfhi(q.x) * cj;
                a2v_ += bflo(q.y) * cj;
                a3 += bfhi(q.y) * cj;
            }
        }
    }

    float f0 = 0.f, f1 = 0.f, f2 = 0.f, f3 = 0.f;
    if (active) {
        float di = dinv2[d];
        uint2 sq = x2[d * 16 + g];
        float s0 = bflo(sq.x), s1 = bfhi(sq.x), s2 = bflo(sq.y), s3 = bfhi(sq.y);
        int c4 = g << 2;
        float4 bv = *(const float4*)&b[c4];
        float4 av = *(const float4*)&alpha[c4];
        f0 = di * (a0 + s0 * di) + bv.x; f0 = f0 >= 0.f ? f0 : av.x * f0;
        f1 = di * (a1v_ + s1 * di) + bv.y; f1 = f1 >= 0.f ? f1 : av.y * f1;
        f2 = di * (a2v_ + s2 * di) + bv.z; f2 = f2 >= 0.f ? f2 : av.z * f2;
        f3 = di * (a3 + s3 * di) + bv.w; f3 = f3 >= 0.f ? f3 : av.w * f3;
    }
    if (slot >= 8)
        *(float4*)&fs[(slot - 8) * 64 + (g << 2)] = make_float4(f0, f1, f2, f3);
    __syncthreads();
    if (slot < 8 && active) {
        float4 p = *(const float4*)&fs[slot * 64 + (g << 2)];
        ((float4*)out)[j * 16 + g] = make_float4(0.5f * (f0 + p.x), 0.5f * (f1 + p.y),
                                                 0.5f * (f2 + p.z), 0.5f * (f3 + p.w));
    }
}

extern "C" void kernel_launch(void* const* d_in, const int* in_sizes, int n_in,
                              void* d_out, int out_size, void* d_ws, size_t ws_size,
                              hipStream_t stream) {
    const float* x  = (const float*)d_in[0];
    const int*   ei = (const int*)d_in[1];
    const float* ew = (const float*)d_in[2];
    const int*   et = (const int*)d_in[3];
    const float* W1 = (const float*)d_in[4];
    const float* b1 = (const float*)d_in[5];
    const float* a1 = (const float*)d_in[6];
    const float* W2 = (const float*)d_in[7];
    const float* b2 = (const float*)d_in[8];
    const float* a2 = (const float*)d_in[9];

    const int N = in_sizes[0] / 128;   // 100000
    const int E = in_sizes[1] / 2;     // 1600000
    const int* src = ei;
    const int* dst = ei + E;

    // Workspace (u32 words), ~91 MB + 80KB frags:
    //   dinv1 N | dinv2 N | xb1 64N | xb2 32N | cnt N | ell 128N
    //   | w1p_hi 8192 | w1p_lo 8192 | w2p 4096
    float*    ws     = (float*)d_ws;
    float*    dinv1  = ws;
    float*    dinv2  = dinv1 + N;
    unsigned* xb1    = (unsigned*)(dinv2 + N);
    unsigned* xb2    = xb1 + (size_t)N * 64;
    int*      cnt    = (int*)(xb2 + (size_t)N * 32);
    int2*     ell    = (int2*)(cnt + N);
    unsigned* w1p_hi = (unsigned*)(ell + (size_t)N * ELL_CAP);
    unsigned* w1p_lo = w1p_hi + 8192;
    unsigned* w2p    = w1p_lo + 8192;

    const int G_ell  = (E / 4 + 255) / 256;   // 1563
    const int G_gemm = (N + 63) / 64;         // 1563

    k_prep<<<48 + (N + 255) / 256, 256, 0, stream>>>(W1, W2, w1p_hi, w1p_lo,
                                                     w2p, cnt, N);

    k_ellgemm<<<G_ell + G_gemm, 256, 0, stream>>>(
        src, dst, et, ew, cnt, ell, E, x, w1p_hi, w1p_lo,
        (unsigned short*)xb1, N, G_ell);

    k_dinv<<<(N + 15) / 16, 256, 0, stream>>>(cnt, ell, dinv1, dinv2, N);

    k_g1g2<<<(N + 15) / 16, 256, 0, stream>>>(cnt, ell, xb1, dinv1, b1, a1,
                                              w2p, (unsigned short*)xb2, N);

    k_g2h<<<(N / 2 + 7) / 8, 256, 0, stream>>>(cnt, ell, xb2, dinv2, b2, a2,
                                               (float*)d_out, N / 2);
}